// Round 1
// baseline (106.160 us; speedup 1.0000x reference)
//
#include <hip/hip_runtime.h>

#define NODES 4096
#define NDIM  512
#define HID   4096

typedef __attribute__((ext_vector_type(8))) short bf16x8;
typedef __attribute__((ext_vector_type(4))) float f32x4;

__device__ __forceinline__ float b2f(short v) {
  union { unsigned int u; float f; } c;
  c.u = ((unsigned int)(unsigned short)v) << 16;
  return c.f;
}
__device__ __forceinline__ short f2b(float f) {
  union { float f; unsigned int u; } c; c.f = f;
  unsigned int r = c.u + 0x7fffu + ((c.u >> 16) & 1u);  // round-nearest-even
  return (short)(r >> 16);
}

// ---- K0a: cast x (fp32) -> bf16 ----
__global__ __launch_bounds__(256) void k_cast_x(const float* __restrict__ x,
                                                short* __restrict__ xb) {
  int i = (blockIdx.x * 256 + threadIdx.x) * 4;
  float4 v = *(const float4*)(x + i);
  short4 o;
  o.x = f2b(v.x); o.y = f2b(v.y); o.z = f2b(v.z); o.w = f2b(v.w);
  *(short4*)(xb + i) = o;
}

// ---- K0b: transpose+cast W1 [512][4096] fp32 -> W1T [4096][512] bf16 ----
__global__ __launch_bounds__(256) void k_transpose_w1(const float* __restrict__ W1,
                                                      short* __restrict__ w1t) {
  __shared__ float tile[32][33];
  int n0 = blockIdx.x * 32;   // 128 blocks
  int k0 = blockIdx.y * 32;   // 16 blocks
  int tx = threadIdx.x & 31, ty = threadIdx.x >> 5;  // 32 x 8
  #pragma unroll
  for (int j = 0; j < 4; ++j) {
    int kk = ty + j * 8;
    tile[kk][tx] = W1[(size_t)(k0 + kk) * HID + n0 + tx];
  }
  __syncthreads();
  #pragma unroll
  for (int j = 0; j < 4; ++j) {
    int nn = ty + j * 8;
    w1t[(size_t)(n0 + nn) * NDIM + k0 + tx] = f2b(tile[tx][nn]);
  }
}

// ---- K0c: init accumulators: a = 0, s = N*b2, uacc = b3 ----
__global__ __launch_bounds__(256) void k_init(const float* __restrict__ b2,
                                              const float* __restrict__ b3,
                                              float* __restrict__ a,
                                              float* __restrict__ s,
                                              float* __restrict__ u) {
  int j = blockIdx.x * 256 + threadIdx.x;
  a[j] = 0.0f;
  s[j] = (float)NODES * b2[j];
  u[j] = b3[j];
}

// ---- K1: A = relu(x @ W1 + b1) (bf16 MFMA), fused column sums -> colsum ----
// xb: [4096][512] bf16, w1t: [4096][512] bf16 (K-major), Aout: [4096][4096] bf16
__global__ __launch_bounds__(256) void k_gemm1(const short* __restrict__ xb,
                                               const short* __restrict__ w1t,
                                               const float* __restrict__ b1,
                                               short* __restrict__ Aout,
                                               float* __restrict__ colsum) {
  __shared__ short As[128 * 32];
  __shared__ short Bs[128 * 32];
  __shared__ float csum[128];

  const int tid  = threadIdx.x;
  const int lane = tid & 63;
  const int w    = tid >> 6;        // wave 0..3
  const int wr   = w >> 1, wc = w & 1;
  const int brow = blockIdx.y * 128, bcol = blockIdx.x * 128;

  f32x4 acc[4][4];
  #pragma unroll
  for (int i = 0; i < 4; ++i)
    #pragma unroll
    for (int j = 0; j < 4; ++j)
      acc[i][j] = (f32x4){0.f, 0.f, 0.f, 0.f};

  if (tid < 128) csum[tid] = 0.f;

  const int fr = lane & 15;
  const int fk = (lane >> 4) * 8;   // 8 consecutive k per lane

  for (int kt = 0; kt < NDIM / 32; ++kt) {
    __syncthreads();   // prev iter's fragment reads done before overwrite
    #pragma unroll
    for (int j = 0; j < 2; ++j) {
      int off = (j * 4 + w) * 1024 + lane * 16;  // byte offset within 8 KB tile
      int row = off >> 6, cb = off & 63;
      const short* ga = xb + (size_t)(brow + row) * NDIM + kt * 32 + (cb >> 1);
      __builtin_amdgcn_global_load_lds(
          (const __attribute__((address_space(1))) void*)ga,
          (__attribute__((address_space(3))) void*)((char*)As + off), 16, 0, 0);
      const short* gb = w1t + (size_t)(bcol + row) * NDIM + kt * 32 + (cb >> 1);
      __builtin_amdgcn_global_load_lds(
          (const __attribute__((address_space(1))) void*)gb,
          (__attribute__((address_space(3))) void*)((char*)Bs + off), 16, 0, 0);
    }
    __syncthreads();   // compiler drains vmcnt(0) before s_barrier

    bf16x8 af[4], bfr[4];
    #pragma unroll
    for (int mi = 0; mi < 4; ++mi)
      af[mi] = *(const bf16x8*)(As + (wr * 64 + mi * 16 + fr) * 32 + fk);
    #pragma unroll
    for (int ni = 0; ni < 4; ++ni)
      bfr[ni] = *(const bf16x8*)(Bs + (wc * 64 + ni * 16 + fr) * 32 + fk);
    #pragma unroll
    for (int mi = 0; mi < 4; ++mi)
      #pragma unroll
      for (int ni = 0; ni < 4; ++ni)
        acc[mi][ni] = __builtin_amdgcn_mfma_f32_16x16x32_bf16(af[mi], bfr[ni],
                                                              acc[mi][ni], 0, 0, 0);
  }

  // epilogue: bias + relu + bf16 store + column partial sums
  const int rbase = (lane >> 4) * 4;   // C/D: col = lane&15, row = (lane>>4)*4 + reg
  #pragma unroll
  for (int ni = 0; ni < 4; ++ni) {
    int lcol = wc * 64 + ni * 16 + fr;
    int col  = bcol + lcol;
    float bias = b1[col];
    float cl = 0.f;
    #pragma unroll
    for (int mi = 0; mi < 4; ++mi) {
      #pragma unroll
      for (int r = 0; r < 4; ++r) {
        float v = acc[mi][ni][r] + bias;
        v = v > 0.f ? v : 0.f;
        cl += v;
        int grow = brow + wr * 64 + mi * 16 + rbase + r;
        Aout[(size_t)grow * HID + col] = f2b(v);
      }
    }
    atomicAdd(&csum[lcol], cl);
  }
  __syncthreads();
  if (tid < 128) atomicAdd(&colsum[bcol + tid], csum[tid]);
}

// ---- K2/K5: vout[col] (+)= sum_i vin[i] * W[i][col]  (W: [4096][4096] fp32) ----
__global__ __launch_bounds__(256) void k_gemv_at(const float* __restrict__ W,
                                                 const float* __restrict__ vin,
                                                 float* __restrict__ vout) {
  const int col = blockIdx.x * 1024 + threadIdx.x * 4;
  const int r0  = blockIdx.y * 64;
  float4 accv = {0.f, 0.f, 0.f, 0.f};
  const float* base = W + (size_t)r0 * HID + col;
  #pragma unroll 4
  for (int i = 0; i < 64; ++i) {
    float vi = vin[r0 + i];
    float4 wv = *(const float4*)(base + (size_t)i * HID);
    accv.x += vi * wv.x; accv.y += vi * wv.y;
    accv.z += vi * wv.z; accv.w += vi * wv.w;
  }
  atomicAdd(&vout[col + 0], accv.x);
  atomicAdd(&vout[col + 1], accv.y);
  atomicAdd(&vout[col + 2], accv.z);
  atomicAdd(&vout[col + 3], accv.w);
}

// ---- K2b: beta = b2 . s ----
__global__ __launch_bounds__(256) void k_beta(const float* __restrict__ b2,
                                              const float* __restrict__ s,
                                              float* __restrict__ beta) {
  __shared__ float red[4];
  float p = 0.f;
  for (int j = threadIdx.x; j < HID; j += 256) p += b2[j] * s[j];
  #pragma unroll
  for (int o = 32; o > 0; o >>= 1) p += __shfl_down(p, o);
  int lane = threadIdx.x & 63, w = threadIdx.x >> 6;
  if (lane == 0) red[w] = p;
  __syncthreads();
  if (threadIdx.x == 0) beta[0] = red[0] + red[1] + red[2] + red[3];
}

// ---- K3: t[row] = W2[row,:] . s   (row-major dot) ----
__global__ __launch_bounds__(256) void k_gemv_row(const float* __restrict__ W,
                                                  const float* __restrict__ vin,
                                                  float* __restrict__ vout) {
  int w = threadIdx.x >> 6, lane = threadIdx.x & 63;
  int row = blockIdx.x * 4 + w;
  const float* base = W + (size_t)row * HID;
  float p = 0.f;
  for (int j = lane * 4; j < HID; j += 256) {
    float4 wv = *(const float4*)(base + j);
    float4 sv = *(const float4*)(vin + j);
    p += wv.x * sv.x + wv.y * sv.y + wv.z * sv.z + wv.w * sv.w;
  }
  #pragma unroll
  for (int o = 32; o > 0; o >>= 1) p += __shfl_down(p, o);
  if (lane == 0) vout[row] = p;
}

// ---- K4: kv[row] = A[row,:] . t + beta   (A bf16) ----
__global__ __launch_bounds__(256) void k_kv(const short* __restrict__ A,
                                            const float* __restrict__ t,
                                            const float* __restrict__ beta,
                                            float* __restrict__ kv) {
  int w = threadIdx.x >> 6, lane = threadIdx.x & 63;
  int row = blockIdx.x * 4 + w;
  const short* base = A + (size_t)row * HID;
  float p = 0.f;
  for (int j = lane * 8; j < HID; j += 512) {
    bf16x8 av = *(const bf16x8*)(base + j);
    float4 t0 = *(const float4*)(t + j);
    float4 t1 = *(const float4*)(t + j + 4);
    p += b2f(av[0]) * t0.x + b2f(av[1]) * t0.y + b2f(av[2]) * t0.z + b2f(av[3]) * t0.w
       + b2f(av[4]) * t1.x + b2f(av[5]) * t1.y + b2f(av[6]) * t1.z + b2f(av[7]) * t1.w;
  }
  #pragma unroll
  for (int o = 32; o > 0; o >>= 1) p += __shfl_down(p, o);
  if (lane == 0) kv[row] = p + beta[0];
}

// ---- K6: out = relu(uacc) . W4 + b4 ----
__global__ __launch_bounds__(256) void k_final(const float* __restrict__ uacc,
                                               const float* __restrict__ W4,
                                               const float* __restrict__ b4,
                                               float* __restrict__ out) {
  __shared__ float red[4];
  float p = 0.f;
  for (int j = threadIdx.x; j < HID; j += 256) {
    float uv = uacc[j];
    uv = uv > 0.f ? uv : 0.f;
    p += uv * W4[j];
  }
  #pragma unroll
  for (int o = 32; o > 0; o >>= 1) p += __shfl_down(p, o);
  int lane = threadIdx.x & 63, w = threadIdx.x >> 6;
  if (lane == 0) red[w] = p;
  __syncthreads();
  if (threadIdx.x == 0) out[0] = red[0] + red[1] + red[2] + red[3] + b4[0];
}

extern "C" void kernel_launch(void* const* d_in, const int* in_sizes, int n_in,
                              void* d_out, int out_size, void* d_ws, size_t ws_size,
                              hipStream_t stream) {
  const float* x  = (const float*)d_in[0];
  // d_in[1] = edge_index (unused by the reference computation)
  const float* W1 = (const float*)d_in[2];
  const float* b1 = (const float*)d_in[3];
  const float* W2 = (const float*)d_in[4];
  const float* b2 = (const float*)d_in[5];
  const float* W3 = (const float*)d_in[6];
  const float* b3 = (const float*)d_in[7];
  const float* W4 = (const float*)d_in[8];
  const float* b4 = (const float*)d_in[9];
  float* out = (float*)d_out;

  char* ws = (char*)d_ws;
  short* Abf  = (short*)(ws);                 // 4096*4096*2 = 33554432 B
  short* xb   = (short*)(ws + 33554432);      // 4 MB
  short* w1t  = (short*)(ws + 37748736);      // 4 MB
  float* aacc = (float*)(ws + 41943040);      // 16 KB each below
  float* svec = (float*)(ws + 41959424);
  float* tvec = (float*)(ws + 41975808);
  float* kvv  = (float*)(ws + 41992192);
  float* uacc = (float*)(ws + 42008576);
  float* beta = (float*)(ws + 42024960);

  k_cast_x      <<<dim3(NODES * NDIM / 1024), dim3(256), 0, stream>>>(x, xb);
  k_transpose_w1<<<dim3(128, 16),             dim3(256), 0, stream>>>(W1, w1t);
  k_init        <<<dim3(16),                  dim3(256), 0, stream>>>(b2, b3, aacc, svec, uacc);
  k_gemm1       <<<dim3(32, 32),              dim3(256), 0, stream>>>(xb, w1t, b1, Abf, aacc);
  k_gemv_at     <<<dim3(4, 64),               dim3(256), 0, stream>>>(W2, aacc, svec);
  k_beta        <<<dim3(1),                   dim3(256), 0, stream>>>(b2, svec, beta);
  k_gemv_row    <<<dim3(1024),                dim3(256), 0, stream>>>(W2, svec, tvec);
  k_kv          <<<dim3(1024),                dim3(256), 0, stream>>>(Abf, tvec, beta, kvv);
  k_gemv_at     <<<dim3(4, 64),               dim3(256), 0, stream>>>(W3, kvv, uacc);
  k_final       <<<dim3(1),                   dim3(256), 0, stream>>>(uacc, W4, b4, out);
}